// Round 15
// baseline (1806.033 us; speedup 1.0000x reference)
//
#include <hip/hip_runtime.h>
#include <math.h>

namespace {

constexpr int T_STEPS = 512;

typedef _Float16 h8v __attribute__((ext_vector_type(8)));
typedef _Float16 h2v __attribute__((ext_vector_type(2)));
typedef float    f4v __attribute__((ext_vector_type(4)));

// rcp-based activations (R13-proven: IEEE div was ~half the VALU issue).
__device__ __forceinline__ float sigf(float v) {
  return __builtin_amdgcn_rcpf(1.0f + __builtin_amdgcn_exp2f(-1.442695041f * v));
}
__device__ __forceinline__ float tanh_(float v) {
  return 2.0f * __builtin_amdgcn_rcpf(1.0f + __builtin_amdgcn_exp2f(-2.885390082f * v)) - 1.0f;
}

// Pack weights into MFMA B-fragment load order, fp16 (verified on HW R3-R14).
// PA (layer0): frag f = (w*4+q)*6 + ks: gate = 16*(8q+w)+(l&15),
//   k = 32*ks + 8*(l>>4) + j ; ks 0-1 Wih0, ks 2-5 Whh0.
// PB (layer1): 8 ks: 0-3 Wih1, 4-7 Whh1.
__global__ void pack_w(const float* __restrict__ Wih0, const float* __restrict__ Whh0,
                       const float* __restrict__ Wih1, const float* __restrict__ Whh1,
                       _Float16* __restrict__ PA, _Float16* __restrict__ PB) {
  int idx = blockIdx.x * 256 + threadIdx.x;
  if (idx < 98304) {
    int j = idx & 7, l = (idx >> 3) & 63;
    int f = idx >> 9;
    int ks = f % 6, wq = f / 6;
    int q = wq & 3, w = wq >> 2;
    int gate = 16 * (8 * q + w) + (l & 15);
    int k = 32 * ks + ((l >> 4) << 3) + j;
    float v = (k < 64) ? Wih0[gate * 64 + k] : Whh0[gate * 128 + (k - 64)];
    PA[idx] = (_Float16)v;
  } else if (idx < 98304 + 131072) {
    int i = idx - 98304;
    int j = i & 7, l = (i >> 3) & 63;
    int f = i >> 9;
    int ks = f & 7, wq = f >> 3;
    int q = wq & 3, w = wq >> 2;
    int gate = 16 * (8 * q + w) + (l & 15);
    int k = 32 * ks + ((l >> 4) << 3) + j;
    float v = (k < 128) ? Wih1[gate * 128 + k] : Whh1[gate * 128 + (k - 128)];
    PB[i] = (_Float16)v;
  }
}

// R14 schedule, fixed occupancy directive. 64 blocks x 1024 threads (16 waves).
// __launch_bounds__(1024, 4): min 4 waves/EU = exactly ONE block/CU -> 128
// regs/wave budget (R14's waves_per_eu(4,4) + dynamic LDS made the allocator
// assume 2 blocks/CU -> 64 VGPR -> 3.3 MB spill). LAYER-SPLIT: waves 0-7 =
// layer0, 8-15 = layer1; 2 L0 + 2 L1 waves per SIMD overlap trans/MFMA/LDS/L2.
// Fused: iter j = L0 step j || L1 step j-1, ONE barrier/iter. Wave w of its
// group owns units [16w,16w+16) x 4 gates. Weights: Whh1 LDS-resident
// (128 KB); W0 / Wih1 compiler-rematerialized from L2 (~160 KB/step,
// R13-measured OK). c fp32 in registers; lane-local cell update.
__global__ __launch_bounds__(1024, 4) void lstm_block(
    const float* __restrict__ x,
    const _Float16* __restrict__ PA, const _Float16* __restrict__ PB,
    const float* __restrict__ b0, const float* __restrict__ b1,
    const float* __restrict__ Wout, const float* __restrict__ bout,
    float* __restrict__ out) {
  extern __shared__ char smem[];
  h8v* whh = (h8v*)smem;  // Whh1 B-frags: [32 wq][4 ks4][64 l] = 128 KB
  _Float16(*h0t)[4][64][8] = (_Float16(*)[4][64][8])(smem + 131072);          // [2][4][64][8] 8 KB
  _Float16(*h1t)[4][64][8] = (_Float16(*)[4][64][8])(smem + 131072 + 8192);   // 8 KB
  _Float16(*xt)[2][64][8]  = (_Float16(*)[2][64][8])(smem + 131072 + 16384);  // [2][2][64][8] 4 KB

  const int tid = threadIdx.x;
  const int g = blockIdx.x;
  const int wv = tid >> 6, l = tid & 63;
  const int lo = l & 15, hi = l >> 4;
  const bool isL0 = (wv < 8);
  const int w = isL0 ? wv : (wv - 8);
  const int unit = 16 * w + lo;
  const int kb_w = w >> 1;
  const int sub_w = (2 * w + (lo >> 3)) & 3;
  const int lanep = sub_w * 16 + hi * 4;  // + r
  const int jw = lo & 7;

  const h8v* PAv = (const h8v*)PA;
  const h8v* PBv = (const h8v*)PB;

  float br[4];
#pragma unroll
  for (int q = 0; q < 4; ++q)
    br[q] = isL0 ? b0[unit + 128 * q] : b1[unit + 128 * q];
  float cs[4] = {0.f, 0.f, 0.f, 0.f};

  // ---- stage Whh1 fragments into LDS ----
  for (int i = tid; i < 8192; i += 1024) {
    int l2 = i & 63, f = i >> 6;
    int ks4 = f & 3, wq = f >> 2;
    whh[i] = PBv[(wq * 8 + 4 + ks4) * 64 + l2];
  }
  // ---- zero h0t/h1t, stage x(0) ----
  {
    unsigned int* z0 = (unsigned int*)h0t;
    unsigned int* z1 = (unsigned int*)h1t;
    for (int i = tid; i < 2048; i += 1024) { z0[i] = 0u; z1[i] = 0u; }
    if (tid < 512) {
      int row = tid >> 5, kk = (tid & 31) << 1;
      const float* xp = x + (((long)(g * 16 + row)) * T_STEPS + 0) * 64 + kk;
      float2 v = *(const float2*)xp;
      h2v pxv; pxv.x = (_Float16)v.x; pxv.y = (_Float16)v.y;
      *(h2v*)&xt[0][kk >> 5][(((kk >> 3) & 3) * 16) + row][kk & 7] = pxv;
    }
  }
  __syncthreads();

  // Fused: iter j = L0 step j (waves 0-7) || L1 step j-1 (waves 8-15).
  for (int j = 0; j <= T_STEPS; ++j) {
    const int p = j & 1;

    if (isL0) {
      if (j < T_STEPS) {
        // ---- layer 0, step j: reads h0t[p], xt[p]; writes h0t[p^1] ----
        h8v h00 = *(const h8v*)&h0t[p][0][l][0];
        h8v h01 = *(const h8v*)&h0t[p][1][l][0];
        h8v h02 = *(const h8v*)&h0t[p][2][l][0];
        h8v h03 = *(const h8v*)&h0t[p][3][l][0];
        h8v ax0 = *(const h8v*)&xt[p][0][l][0];
        h8v ax1 = *(const h8v*)&xt[p][1][l][0];
        f4v acc[4];
#pragma unroll
        for (int q = 0; q < 4; ++q) {
          const h8v* wp = PAv + (long)((w * 4 + q) * 6) * 64 + l;
          h8v w0 = wp[0], w1 = wp[64], w2 = wp[128];
          h8v w3 = wp[192], w4 = wp[256], w5 = wp[320];
          f4v z = {br[q], br[q], br[q], br[q]};
          z = __builtin_amdgcn_mfma_f32_16x16x32_f16(ax0, w0, z, 0, 0, 0);
          z = __builtin_amdgcn_mfma_f32_16x16x32_f16(ax1, w1, z, 0, 0, 0);
          z = __builtin_amdgcn_mfma_f32_16x16x32_f16(h00, w2, z, 0, 0, 0);
          z = __builtin_amdgcn_mfma_f32_16x16x32_f16(h01, w3, z, 0, 0, 0);
          z = __builtin_amdgcn_mfma_f32_16x16x32_f16(h02, w4, z, 0, 0, 0);
          z = __builtin_amdgcn_mfma_f32_16x16x32_f16(h03, w5, z, 0, 0, 0);
          acc[q] = z;
        }
#pragma unroll
        for (int r = 0; r < 4; ++r) {
          float cn = sigf(acc[1][r]) * cs[r] + sigf(acc[0][r]) * tanh_(acc[2][r]);
          cs[r] = cn;
          float hv = sigf(acc[3][r]) * tanh_(cn);
          h0t[p ^ 1][kb_w][lanep + r][jw] = (_Float16)hv;
        }
        if (j + 1 < T_STEPS) {  // stage x(j+1) -> xt[p^1] (all 512 L0 threads)
          int row = tid >> 5, kk = (tid & 31) << 1;
          const float* xp = x + (((long)(g * 16 + row)) * T_STEPS + (j + 1)) * 64 + kk;
          float2 v = *(const float2*)xp;
          h2v pxv; pxv.x = (_Float16)v.x; pxv.y = (_Float16)v.y;
          *(h2v*)&xt[p ^ 1][kk >> 5][(((kk >> 3) & 3) * 16) + row][kk & 7] = pxv;
        }
      }
    } else {
      if (j >= 1) {
        // ---- layer 1, step j-1: reads h0t[p] (=h0(j-1)), h1t[p]; writes h1t[p^1] ----
        h8v h00 = *(const h8v*)&h0t[p][0][l][0];
        h8v h01 = *(const h8v*)&h0t[p][1][l][0];
        h8v h02 = *(const h8v*)&h0t[p][2][l][0];
        h8v h03 = *(const h8v*)&h0t[p][3][l][0];
        h8v f10 = *(const h8v*)&h1t[p][0][l][0];
        h8v f11 = *(const h8v*)&h1t[p][1][l][0];
        h8v f12 = *(const h8v*)&h1t[p][2][l][0];
        h8v f13 = *(const h8v*)&h1t[p][3][l][0];
        f4v acc[4];
#pragma unroll
        for (int q = 0; q < 4; ++q) {
          const h8v* wip = PBv + (long)((w * 4 + q) * 8) * 64 + l;
          h8v wi0 = wip[0], wi1 = wip[64], wi2 = wip[128], wi3 = wip[192];
          const h8v* wb = &whh[((w * 4 + q) * 4) * 64 + l];
          h8v wh0 = wb[0];
          h8v wh1 = wb[64];
          h8v wh2 = wb[128];
          h8v wh3 = wb[192];
          f4v z = {br[q], br[q], br[q], br[q]};
          z = __builtin_amdgcn_mfma_f32_16x16x32_f16(h00, wi0, z, 0, 0, 0);
          z = __builtin_amdgcn_mfma_f32_16x16x32_f16(h01, wi1, z, 0, 0, 0);
          z = __builtin_amdgcn_mfma_f32_16x16x32_f16(h02, wi2, z, 0, 0, 0);
          z = __builtin_amdgcn_mfma_f32_16x16x32_f16(h03, wi3, z, 0, 0, 0);
          z = __builtin_amdgcn_mfma_f32_16x16x32_f16(f10, wh0, z, 0, 0, 0);
          z = __builtin_amdgcn_mfma_f32_16x16x32_f16(f11, wh1, z, 0, 0, 0);
          z = __builtin_amdgcn_mfma_f32_16x16x32_f16(f12, wh2, z, 0, 0, 0);
          z = __builtin_amdgcn_mfma_f32_16x16x32_f16(f13, wh3, z, 0, 0, 0);
          acc[q] = z;
        }
#pragma unroll
        for (int r = 0; r < 4; ++r) {
          float cn = sigf(acc[1][r]) * cs[r] + sigf(acc[0][r]) * tanh_(acc[2][r]);
          cs[r] = cn;
          float hv = sigf(acc[3][r]) * tanh_(cn);
          h1t[p ^ 1][kb_w][lanep + r][jw] = (_Float16)hv;
        }
      }
    }
    __syncthreads();
  }

  // ---- output projection: y = h1(T-1) . Wout^T + bout ; h1(T-1) in h1t[1] ----
  if (tid < 16) {
    float acc = bout[0];
#pragma unroll 4
    for (int u = 0; u < 128; ++u) {
      float hval = (float)h1t[1][u >> 5][(((u >> 3) & 3) * 16) + tid][u & 7];
      acc = fmaf(hval, Wout[u], acc);
    }
    out[g * 16 + tid] = acc;
  }
}

}  // namespace

extern "C" void kernel_launch(void* const* d_in, const int* in_sizes, int n_in,
                              void* d_out, int out_size, void* d_ws, size_t ws_size,
                              hipStream_t stream) {
  const float* x    = (const float*)d_in[0];
  const float* Wih0 = (const float*)d_in[1];
  const float* Whh0 = (const float*)d_in[2];
  const float* b0   = (const float*)d_in[3];
  const float* Wih1 = (const float*)d_in[4];
  const float* Whh1 = (const float*)d_in[5];
  const float* b1   = (const float*)d_in[6];
  const float* Wout = (const float*)d_in[7];
  const float* bout = (const float*)d_in[8];
  float* out = (float*)d_out;

  char* ws = (char*)d_ws;
  _Float16* PA = (_Float16*)ws;             // 196608 B
  _Float16* PB = (_Float16*)(ws + 196608);  // 262144 B

  const int lds_bytes = 131072 + 8192 + 8192 + 4096;  // 151552
  hipFuncSetAttribute((const void*)lstm_block,
                      hipFuncAttributeMaxDynamicSharedMemorySize, lds_bytes);

  pack_w<<<dim3(896), dim3(256), 0, stream>>>(Wih0, Whh0, Wih1, Whh1, PA, PB);
  lstm_block<<<dim3(64), dim3(1024), lds_bytes, stream>>>(
      x, PA, PB, b0, b1, Wout, bout, out);
}

// Round 16
// 1353.130 us; speedup vs baseline: 1.3347x; 1.3347x over previous
//
#include <hip/hip_runtime.h>
#include <math.h>

namespace {

constexpr int T_STEPS = 512;

typedef _Float16 h8v __attribute__((ext_vector_type(8)));
typedef _Float16 h2v __attribute__((ext_vector_type(2)));
typedef float    f4v __attribute__((ext_vector_type(4)));

// Gate math (R16): weights/biases PRE-SCALED by -log2(e) (i,f,o) and
// -2*log2(e) (g), so MFMA emits z' = -1.4427*z (or -2.885*z) directly.
//   sigma(z)        = rcp(1 + exp2(z'))
//   sigma(i)tanh(g) = (1-e_g) * rcp((1+e_i)(1+e_g))     [shared rcp]
//   sigma(o)tanh(c) = (1-e_c) * rcp((1+e_o)(1+e_c))
// 8 trans/cell (was 10), no per-trans mul. fminf(.,126) clamps the two
// tanh-side exponents: without it e=inf gives (1-inf)*rcp(inf)=NaN; with it
// the limit degrades to +-0 (correct saturation).

// Pack weights into MFMA B-fragment load order, fp16, PRE-SCALED per gate
// type (layout HW-verified R3-R15; scaling is new).
// PA (layer0): frag f = (w*4+q)*6 + ks: gate = 16*(8q+w)+(l&15),
//   k = 32*ks + 8*(l>>4) + j ; ks 0-1 Wih0, ks 2-5 Whh0.
// PB (layer1): 8 ks: 0-3 Wih1, 4-7 Whh1. Gate type = gate>>7 (0=i,1=f,2=g,3=o).
__global__ void pack_w(const float* __restrict__ Wih0, const float* __restrict__ Whh0,
                       const float* __restrict__ Wih1, const float* __restrict__ Whh1,
                       _Float16* __restrict__ PA, _Float16* __restrict__ PB) {
  int idx = blockIdx.x * 256 + threadIdx.x;
  if (idx < 98304) {
    int j = idx & 7, l = (idx >> 3) & 63;
    int f = idx >> 9;
    int ks = f % 6, wq = f / 6;
    int q = wq & 3, w = wq >> 2;
    int gate = 16 * (8 * q + w) + (l & 15);
    int k = 32 * ks + ((l >> 4) << 3) + j;
    float v = (k < 64) ? Wih0[gate * 64 + k] : Whh0[gate * 128 + (k - 64)];
    float s = ((gate >> 7) == 2) ? -2.885390082f : -1.442695041f;
    PA[idx] = (_Float16)(v * s);
  } else if (idx < 98304 + 131072) {
    int i = idx - 98304;
    int j = i & 7, l = (i >> 3) & 63;
    int f = i >> 9;
    int ks = f & 7, wq = f >> 3;
    int q = wq & 3, w = wq >> 2;
    int gate = 16 * (8 * q + w) + (l & 15);
    int k = 32 * ks + ((l >> 4) << 3) + j;
    float v = (k < 128) ? Wih1[gate * 128 + k] : Whh1[gate * 128 + (k - 128)];
    float s = ((gate >> 7) == 2) ? -2.885390082f : -1.442695041f;
    PB[i] = (_Float16)(v * s);
  }
}

// Fused LSTM cell from pre-scaled gate pre-activations (zi',zf',zg',zo').
__device__ __forceinline__ void cell_update(float zi, float zf, float zg, float zo,
                                            float& c, float& h) {
  float ei = __builtin_amdgcn_exp2f(zi);
  float ef = __builtin_amdgcn_exp2f(zf);
  float eg = __builtin_amdgcn_exp2f(fminf(zg, 126.0f));
  float eo = __builtin_amdgcn_exp2f(zo);
  float ig = (1.0f - eg) * __builtin_amdgcn_rcpf((1.0f + ei) * (1.0f + eg));
  float cn = c * __builtin_amdgcn_rcpf(1.0f + ef) + ig;
  c = cn;
  float ec = __builtin_amdgcn_exp2f(fminf(-2.885390082f * cn, 126.0f));
  h = (1.0f - ec) * __builtin_amdgcn_rcpf((1.0f + eo) * (1.0f + ec));
}

// R13 structure verbatim (best: 1291us) with pre-scaled weights + fused-rcp
// cell updates (single-variable A/B). 64 blocks x 512 threads (8 waves,
// 2/SIMD), 1 block/CU. Fused pipeline: iter j = layer0 step j + layer1 step
// j-1 (independent), ONE barrier/iter; wave w owns units [16w,16w+16) x 4
// gate types for both layers; lane-local cell update, c fp32 in registers.
// Weights: W0+Wih1 compiler-rematerialized from L2 (~160 KB/step, measured
// OK); Whh1 LDS-resident (128 KB).
__global__ __attribute__((amdgpu_waves_per_eu(2, 2))) __launch_bounds__(512)
void lstm_block(
    const float* __restrict__ x,
    const _Float16* __restrict__ PA, const _Float16* __restrict__ PB,
    const float* __restrict__ b0, const float* __restrict__ b1,
    const float* __restrict__ Wout, const float* __restrict__ bout,
    float* __restrict__ out) {
  extern __shared__ char smem[];
  h8v* whh = (h8v*)smem;  // Whh1 B-frags: [32 wq][4 ks4][64 l] = 128 KB
  _Float16(*h0t)[4][64][8] = (_Float16(*)[4][64][8])(smem + 131072);          // [2][4][64][8] 8 KB
  _Float16(*h1t)[4][64][8] = (_Float16(*)[4][64][8])(smem + 131072 + 8192);   // 8 KB
  _Float16(*xt)[2][64][8]  = (_Float16(*)[2][64][8])(smem + 131072 + 16384);  // [2][2][64][8] 4 KB

  const int tid = threadIdx.x;
  const int g = blockIdx.x;
  const int w = tid >> 6, l = tid & 63;
  const int lo = l & 15, hi = l >> 4;
  const int unit = 16 * w + lo;
  const int kb_w = w >> 1;
  const int sub_w = (2 * w + (lo >> 3)) & 3;
  const int lanep = sub_w * 16 + hi * 4;  // + r
  const int jw = lo & 7;

  // ---- persistent register weights (compiler may remat -- measured OK) ----
  const h8v* PAv = (const h8v*)PA;
  const h8v* PBv = (const h8v*)PB;
  h8v W0[4][6], W1[4][4];
#pragma unroll
  for (int q = 0; q < 4; ++q) {
#pragma unroll
    for (int ks = 0; ks < 6; ++ks) W0[q][ks] = PAv[((w * 4 + q) * 6 + ks) * 64 + l];
#pragma unroll
    for (int ks = 0; ks < 4; ++ks) W1[q][ks] = PBv[((w * 4 + q) * 8 + ks) * 64 + l];
  }
#pragma unroll
  for (int q = 0; q < 4; ++q) {
#pragma unroll
    for (int ks = 0; ks < 6; ++ks) asm volatile("" : "+v"(W0[q][ks]));
#pragma unroll
    for (int ks = 0; ks < 4; ++ks) asm volatile("" : "+v"(W1[q][ks]));
  }
  // biases pre-scaled to match the weight scaling
  float bA[4], bB[4];
#pragma unroll
  for (int q = 0; q < 4; ++q) {
    float s = (q == 2) ? -2.885390082f : -1.442695041f;
    bA[q] = b0[unit + 128 * q] * s;
    bB[q] = b1[unit + 128 * q] * s;
  }
  float c0[4] = {0.f, 0.f, 0.f, 0.f}, c1[4] = {0.f, 0.f, 0.f, 0.f};

  // ---- stage Whh1 fragments into LDS ----
  for (int i = tid; i < 8192; i += 512) {
    int l2 = i & 63, f = i >> 6;
    int ks4 = f & 3, wq = f >> 2;
    whh[i] = PBv[(wq * 8 + 4 + ks4) * 64 + l2];
  }
  // ---- zero h0t/h1t, stage x(0) ----
  {
    unsigned int* z0 = (unsigned int*)h0t;
    unsigned int* z1 = (unsigned int*)h1t;
    for (int i = tid; i < 2048; i += 512) { z0[i] = 0u; z1[i] = 0u; }
    int row = tid >> 5, kk = (tid & 31) << 1;
    const float* xp = x + (((long)(g * 16 + row)) * T_STEPS + 0) * 64 + kk;
    float2 v = *(const float2*)xp;
    h2v pxv; pxv.x = (_Float16)v.x; pxv.y = (_Float16)v.y;
    *(h2v*)&xt[0][kk >> 5][(((kk >> 3) & 3) * 16) + row][kk & 7] = pxv;
  }
  __syncthreads();

  // Fused: iter j = A(j) [layer0 step j] + B(j-1) [layer1 step j-1].
  for (int j = 0; j <= T_STEPS; ++j) {
    const int p = j & 1;

    // shared h0(j-1) fragments (A-operand for BOTH layers)
    h8v h00 = *(const h8v*)&h0t[p][0][l][0];
    h8v h01 = *(const h8v*)&h0t[p][1][l][0];
    h8v h02 = *(const h8v*)&h0t[p][2][l][0];
    h8v h03 = *(const h8v*)&h0t[p][3][l][0];

    if (j < T_STEPS) {
      // ---- A(j): layer 0 computes h0(j) ----
      h8v ax0 = *(const h8v*)&xt[p][0][l][0];
      h8v ax1 = *(const h8v*)&xt[p][1][l][0];
      f4v accA[4];
#pragma unroll
      for (int q = 0; q < 4; ++q) {
        f4v z = {bA[q], bA[q], bA[q], bA[q]};
        z = __builtin_amdgcn_mfma_f32_16x16x32_f16(ax0, W0[q][0], z, 0, 0, 0);
        z = __builtin_amdgcn_mfma_f32_16x16x32_f16(ax1, W0[q][1], z, 0, 0, 0);
        z = __builtin_amdgcn_mfma_f32_16x16x32_f16(h00, W0[q][2], z, 0, 0, 0);
        z = __builtin_amdgcn_mfma_f32_16x16x32_f16(h01, W0[q][3], z, 0, 0, 0);
        z = __builtin_amdgcn_mfma_f32_16x16x32_f16(h02, W0[q][4], z, 0, 0, 0);
        z = __builtin_amdgcn_mfma_f32_16x16x32_f16(h03, W0[q][5], z, 0, 0, 0);
        accA[q] = z;
      }
#pragma unroll
      for (int r = 0; r < 4; ++r) {
        float hv;
        cell_update(accA[0][r], accA[1][r], accA[2][r], accA[3][r], c0[r], hv);
        h0t[p ^ 1][kb_w][lanep + r][jw] = (_Float16)hv;
      }
      if (j + 1 < T_STEPS) {  // stage x(j+1)
        int row = tid >> 5, kk = (tid & 31) << 1;
        const float* xp = x + (((long)(g * 16 + row)) * T_STEPS + (j + 1)) * 64 + kk;
        float2 v = *(const float2*)xp;
        h2v pxv; pxv.x = (_Float16)v.x; pxv.y = (_Float16)v.y;
        *(h2v*)&xt[p ^ 1][kk >> 5][(((kk >> 3) & 3) * 16) + row][kk & 7] = pxv;
      }
    }

    if (j >= 1) {
      // ---- B(j-1): layer 1 computes h1(j-1) ----
      h8v f10 = *(const h8v*)&h1t[p][0][l][0];
      h8v f11 = *(const h8v*)&h1t[p][1][l][0];
      h8v f12 = *(const h8v*)&h1t[p][2][l][0];
      h8v f13 = *(const h8v*)&h1t[p][3][l][0];
      f4v accB[4];
#pragma unroll
      for (int q = 0; q < 4; ++q) {
        const h8v* wb = &whh[((w * 4 + q) * 4) * 64 + l];
        h8v wh0 = wb[0];
        h8v wh1 = wb[64];
        h8v wh2 = wb[128];
        h8v wh3 = wb[192];
        f4v z = {bB[q], bB[q], bB[q], bB[q]};
        z = __builtin_amdgcn_mfma_f32_16x16x32_f16(h00, W1[q][0], z, 0, 0, 0);
        z = __builtin_amdgcn_mfma_f32_16x16x32_f16(h01, W1[q][1], z, 0, 0, 0);
        z = __builtin_amdgcn_mfma_f32_16x16x32_f16(h02, W1[q][2], z, 0, 0, 0);
        z = __builtin_amdgcn_mfma_f32_16x16x32_f16(h03, W1[q][3], z, 0, 0, 0);
        z = __builtin_amdgcn_mfma_f32_16x16x32_f16(f10, wh0, z, 0, 0, 0);
        z = __builtin_amdgcn_mfma_f32_16x16x32_f16(f11, wh1, z, 0, 0, 0);
        z = __builtin_amdgcn_mfma_f32_16x16x32_f16(f12, wh2, z, 0, 0, 0);
        z = __builtin_amdgcn_mfma_f32_16x16x32_f16(f13, wh3, z, 0, 0, 0);
        accB[q] = z;
      }
#pragma unroll
      for (int r = 0; r < 4; ++r) {
        float hv;
        cell_update(accB[0][r], accB[1][r], accB[2][r], accB[3][r], c1[r], hv);
        h1t[p ^ 1][kb_w][lanep + r][jw] = (_Float16)hv;
      }
    }
    __syncthreads();
  }

  // ---- output projection: y = h1(T-1) . Wout^T + bout ; h1(T-1) in h1t[1] ----
  if (tid < 16) {
    float acc = bout[0];
#pragma unroll 4
    for (int u = 0; u < 128; ++u) {
      float hval = (float)h1t[1][u >> 5][(((u >> 3) & 3) * 16) + tid][u & 7];
      acc = fmaf(hval, Wout[u], acc);
    }
    out[g * 16 + tid] = acc;
  }
}

}  // namespace

extern "C" void kernel_launch(void* const* d_in, const int* in_sizes, int n_in,
                              void* d_out, int out_size, void* d_ws, size_t ws_size,
                              hipStream_t stream) {
  const float* x    = (const float*)d_in[0];
  const float* Wih0 = (const float*)d_in[1];
  const float* Whh0 = (const float*)d_in[2];
  const float* b0   = (const float*)d_in[3];
  const float* Wih1 = (const float*)d_in[4];
  const float* Whh1 = (const float*)d_in[5];
  const float* b1   = (const float*)d_in[6];
  const float* Wout = (const float*)d_in[7];
  const float* bout = (const float*)d_in[8];
  float* out = (float*)d_out;

  char* ws = (char*)d_ws;
  _Float16* PA = (_Float16*)ws;             // 196608 B
  _Float16* PB = (_Float16*)(ws + 196608);  // 262144 B

  const int lds_bytes = 131072 + 8192 + 8192 + 4096;  // 151552
  hipFuncSetAttribute((const void*)lstm_block,
                      hipFuncAttributeMaxDynamicSharedMemorySize, lds_bytes);

  pack_w<<<dim3(896), dim3(256), 0, stream>>>(Wih0, Whh0, Wih1, Whh1, PA, PB);
  lstm_block<<<dim3(64), dim3(512), lds_bytes, stream>>>(
      x, PA, PB, b0, b1, Wout, bout, out);
}

// Round 17
// 1299.301 us; speedup vs baseline: 1.3900x; 1.0414x over previous
//
#include <hip/hip_runtime.h>
#include <math.h>

namespace {

constexpr int T_STEPS = 512;

typedef _Float16 h8v __attribute__((ext_vector_type(8)));
typedef _Float16 h2v __attribute__((ext_vector_type(2)));
typedef float    f4v __attribute__((ext_vector_type(4)));

// rcp-based activations (R13-proven; R16's fused form lengthened the serial
// chain and regressed -- reverted).
__device__ __forceinline__ float sigf(float v) {
  return __builtin_amdgcn_rcpf(1.0f + __builtin_amdgcn_exp2f(-1.442695041f * v));
}
__device__ __forceinline__ float tanh_(float v) {
  return 2.0f * __builtin_amdgcn_rcpf(1.0f + __builtin_amdgcn_exp2f(-2.885390082f * v)) - 1.0f;
}

// Pack weights into MFMA B-fragment load order, fp16 (verified on HW R3-R16).
// PA (layer0): frag f = (w*4+q)*6 + ks: gate = 16*(8q+w)+(l&15),
//   k = 32*ks + 8*(l>>4) + j ; ks 0-1 Wih0, ks 2-5 Whh0.
// PB (layer1): 8 ks: 0-3 Wih1, 4-7 Whh1.
__global__ void pack_w(const float* __restrict__ Wih0, const float* __restrict__ Whh0,
                       const float* __restrict__ Wih1, const float* __restrict__ Whh1,
                       _Float16* __restrict__ PA, _Float16* __restrict__ PB) {
  int idx = blockIdx.x * 256 + threadIdx.x;
  if (idx < 98304) {
    int j = idx & 7, l = (idx >> 3) & 63;
    int f = idx >> 9;
    int ks = f % 6, wq = f / 6;
    int q = wq & 3, w = wq >> 2;
    int gate = 16 * (8 * q + w) + (l & 15);
    int k = 32 * ks + ((l >> 4) << 3) + j;
    float v = (k < 64) ? Wih0[gate * 64 + k] : Whh0[gate * 128 + (k - 64)];
    PA[idx] = (_Float16)v;
  } else if (idx < 98304 + 131072) {
    int i = idx - 98304;
    int j = i & 7, l = (i >> 3) & 63;
    int f = i >> 9;
    int ks = f & 7, wq = f >> 3;
    int q = wq & 3, w = wq >> 2;
    int gate = 16 * (8 * q + w) + (l & 15);
    int k = 32 * ks + ((l >> 4) << 3) + j;
    float v = (k < 128) ? Wih1[gate * 128 + k] : Whh1[gate * 128 + (k - 128)];
    PB[i] = (_Float16)v;
  }
}

// R13 structure (1291us) + WAVE-PARITY PHASE STAGGER (single-variable A/B).
// R16 post-mortem: kernel is overlap/latency-bound -- all waves phase-align
// between barriers (LDS storm, then VALU storm; pipes serialize). A(j) and
// B(j-1) are independent, so odd waves run B THEN A while even waves run
// A THEN B: each SIMD's two waves are now in opposite phases, overlapping
// LDS-port work with MFMA/trans work by construction.
// 64 blocks x 512 threads (8 waves, 2/SIMD), 1 block/CU, ONE barrier/iter;
// wave w owns units [16w,16w+16) x 4 gates for both layers; lane-local cell
// update, c fp32 in registers. Weights: W0+Wih1 compiler-remat from L2
// (~160 KB/step, measured OK); Whh1 LDS-resident (128 KB).
__global__ __attribute__((amdgpu_waves_per_eu(2, 2))) __launch_bounds__(512)
void lstm_block(
    const float* __restrict__ x,
    const _Float16* __restrict__ PA, const _Float16* __restrict__ PB,
    const float* __restrict__ b0, const float* __restrict__ b1,
    const float* __restrict__ Wout, const float* __restrict__ bout,
    float* __restrict__ out) {
  extern __shared__ char smem[];
  h8v* whh = (h8v*)smem;  // Whh1 B-frags: [32 wq][4 ks4][64 l] = 128 KB
  _Float16(*h0t)[4][64][8] = (_Float16(*)[4][64][8])(smem + 131072);          // [2][4][64][8] 8 KB
  _Float16(*h1t)[4][64][8] = (_Float16(*)[4][64][8])(smem + 131072 + 8192);   // 8 KB
  _Float16(*xt)[2][64][8]  = (_Float16(*)[2][64][8])(smem + 131072 + 16384);  // [2][2][64][8] 4 KB

  const int tid = threadIdx.x;
  const int g = blockIdx.x;
  const int w = tid >> 6, l = tid & 63;
  const int lo = l & 15, hi = l >> 4;
  const int unit = 16 * w + lo;
  const int kb_w = w >> 1;
  const int sub_w = (2 * w + (lo >> 3)) & 3;
  const int lanep = sub_w * 16 + hi * 4;  // + r
  const int jw = lo & 7;

  // ---- persistent register weights (compiler may remat -- measured OK) ----
  const h8v* PAv = (const h8v*)PA;
  const h8v* PBv = (const h8v*)PB;
  h8v W0[4][6], W1[4][4];
#pragma unroll
  for (int q = 0; q < 4; ++q) {
#pragma unroll
    for (int ks = 0; ks < 6; ++ks) W0[q][ks] = PAv[((w * 4 + q) * 6 + ks) * 64 + l];
#pragma unroll
    for (int ks = 0; ks < 4; ++ks) W1[q][ks] = PBv[((w * 4 + q) * 8 + ks) * 64 + l];
  }
#pragma unroll
  for (int q = 0; q < 4; ++q) {
#pragma unroll
    for (int ks = 0; ks < 6; ++ks) asm volatile("" : "+v"(W0[q][ks]));
#pragma unroll
    for (int ks = 0; ks < 4; ++ks) asm volatile("" : "+v"(W1[q][ks]));
  }
  float bA[4], bB[4];
#pragma unroll
  for (int q = 0; q < 4; ++q) { bA[q] = b0[unit + 128 * q]; bB[q] = b1[unit + 128 * q]; }
  float c0[4] = {0.f, 0.f, 0.f, 0.f}, c1[4] = {0.f, 0.f, 0.f, 0.f};

  // ---- stage Whh1 fragments into LDS ----
  for (int i = tid; i < 8192; i += 512) {
    int l2 = i & 63, f = i >> 6;
    int ks4 = f & 3, wq = f >> 2;
    whh[i] = PBv[(wq * 8 + 4 + ks4) * 64 + l2];
  }
  // ---- zero h0t/h1t, stage x(0) ----
  {
    unsigned int* z0 = (unsigned int*)h0t;
    unsigned int* z1 = (unsigned int*)h1t;
    for (int i = tid; i < 2048; i += 512) { z0[i] = 0u; z1[i] = 0u; }
    int row = tid >> 5, kk = (tid & 31) << 1;
    const float* xp = x + (((long)(g * 16 + row)) * T_STEPS + 0) * 64 + kk;
    float2 v = *(const float2*)xp;
    h2v pxv; pxv.x = (_Float16)v.x; pxv.y = (_Float16)v.y;
    *(h2v*)&xt[0][kk >> 5][(((kk >> 3) & 3) * 16) + row][kk & 7] = pxv;
  }
  __syncthreads();

  // Fused: iter j = A(j) [layer0 step j] + B(j-1) [layer1 step j-1].
  // Even waves: A then B. Odd waves: B then A (phase stagger).
  for (int j = 0; j <= T_STEPS; ++j) {
    const int p = j & 1;

    // shared h0(j-1) fragments (A-operand for BOTH layers)
    h8v h00 = *(const h8v*)&h0t[p][0][l][0];
    h8v h01 = *(const h8v*)&h0t[p][1][l][0];
    h8v h02 = *(const h8v*)&h0t[p][2][l][0];
    h8v h03 = *(const h8v*)&h0t[p][3][l][0];

    auto phaseA = [&]() {
      if (j < T_STEPS) {
        h8v ax0 = *(const h8v*)&xt[p][0][l][0];
        h8v ax1 = *(const h8v*)&xt[p][1][l][0];
        f4v accA[4];
#pragma unroll
        for (int q = 0; q < 4; ++q) {
          f4v z = {bA[q], bA[q], bA[q], bA[q]};
          z = __builtin_amdgcn_mfma_f32_16x16x32_f16(ax0, W0[q][0], z, 0, 0, 0);
          z = __builtin_amdgcn_mfma_f32_16x16x32_f16(ax1, W0[q][1], z, 0, 0, 0);
          z = __builtin_amdgcn_mfma_f32_16x16x32_f16(h00, W0[q][2], z, 0, 0, 0);
          z = __builtin_amdgcn_mfma_f32_16x16x32_f16(h01, W0[q][3], z, 0, 0, 0);
          z = __builtin_amdgcn_mfma_f32_16x16x32_f16(h02, W0[q][4], z, 0, 0, 0);
          z = __builtin_amdgcn_mfma_f32_16x16x32_f16(h03, W0[q][5], z, 0, 0, 0);
          accA[q] = z;
        }
#pragma unroll
        for (int r = 0; r < 4; ++r) {
          float cn = sigf(accA[1][r]) * c0[r] + sigf(accA[0][r]) * tanh_(accA[2][r]);
          c0[r] = cn;
          float hv = sigf(accA[3][r]) * tanh_(cn);
          h0t[p ^ 1][kb_w][lanep + r][jw] = (_Float16)hv;
        }
        if (j + 1 < T_STEPS) {  // stage x(j+1)
          int row = tid >> 5, kk = (tid & 31) << 1;
          const float* xp = x + (((long)(g * 16 + row)) * T_STEPS + (j + 1)) * 64 + kk;
          float2 v = *(const float2*)xp;
          h2v pxv; pxv.x = (_Float16)v.x; pxv.y = (_Float16)v.y;
          *(h2v*)&xt[p ^ 1][kk >> 5][(((kk >> 3) & 3) * 16) + row][kk & 7] = pxv;
        }
      }
    };

    auto phaseB = [&]() {
      if (j >= 1) {
        h8v f10 = *(const h8v*)&h1t[p][0][l][0];
        h8v f11 = *(const h8v*)&h1t[p][1][l][0];
        h8v f12 = *(const h8v*)&h1t[p][2][l][0];
        h8v f13 = *(const h8v*)&h1t[p][3][l][0];
        f4v accB[4];
#pragma unroll
        for (int q = 0; q < 4; ++q) {
          const h8v* wb = &whh[((w * 4 + q) * 4) * 64 + l];
          h8v wh0 = wb[0];
          h8v wh1 = wb[64];
          h8v wh2 = wb[128];
          h8v wh3 = wb[192];
          f4v z = {bB[q], bB[q], bB[q], bB[q]};
          z = __builtin_amdgcn_mfma_f32_16x16x32_f16(h00, W1[q][0], z, 0, 0, 0);
          z = __builtin_amdgcn_mfma_f32_16x16x32_f16(h01, W1[q][1], z, 0, 0, 0);
          z = __builtin_amdgcn_mfma_f32_16x16x32_f16(h02, W1[q][2], z, 0, 0, 0);
          z = __builtin_amdgcn_mfma_f32_16x16x32_f16(h03, W1[q][3], z, 0, 0, 0);
          z = __builtin_amdgcn_mfma_f32_16x16x32_f16(f10, wh0, z, 0, 0, 0);
          z = __builtin_amdgcn_mfma_f32_16x16x32_f16(f11, wh1, z, 0, 0, 0);
          z = __builtin_amdgcn_mfma_f32_16x16x32_f16(f12, wh2, z, 0, 0, 0);
          z = __builtin_amdgcn_mfma_f32_16x16x32_f16(f13, wh3, z, 0, 0, 0);
          accB[q] = z;
        }
#pragma unroll
        for (int r = 0; r < 4; ++r) {
          float cn = sigf(accB[1][r]) * c1[r] + sigf(accB[0][r]) * tanh_(accB[2][r]);
          c1[r] = cn;
          float hv = sigf(accB[3][r]) * tanh_(cn);
          h1t[p ^ 1][kb_w][lanep + r][jw] = (_Float16)hv;
        }
      }
    };

    if (w & 1) { phaseB(); phaseA(); }
    else       { phaseA(); phaseB(); }
    __syncthreads();
  }

  // ---- output projection: y = h1(T-1) . Wout^T + bout ; h1(T-1) in h1t[1] ----
  if (tid < 16) {
    float acc = bout[0];
#pragma unroll 4
    for (int u = 0; u < 128; ++u) {
      float hval = (float)h1t[1][u >> 5][(((u >> 3) & 3) * 16) + tid][u & 7];
      acc = fmaf(hval, Wout[u], acc);
    }
    out[g * 16 + tid] = acc;
  }
}

}  // namespace

extern "C" void kernel_launch(void* const* d_in, const int* in_sizes, int n_in,
                              void* d_out, int out_size, void* d_ws, size_t ws_size,
                              hipStream_t stream) {
  const float* x    = (const float*)d_in[0];
  const float* Wih0 = (const float*)d_in[1];
  const float* Whh0 = (const float*)d_in[2];
  const float* b0   = (const float*)d_in[3];
  const float* Wih1 = (const float*)d_in[4];
  const float* Whh1 = (const float*)d_in[5];
  const float* b1   = (const float*)d_in[6];
  const float* Wout = (const float*)d_in[7];
  const float* bout = (const float*)d_in[8];
  float* out = (float*)d_out;

  char* ws = (char*)d_ws;
  _Float16* PA = (_Float16*)ws;             // 196608 B
  _Float16* PB = (_Float16*)(ws + 196608);  // 262144 B

  const int lds_bytes = 131072 + 8192 + 8192 + 4096;  // 151552
  hipFuncSetAttribute((const void*)lstm_block,
                      hipFuncAttributeMaxDynamicSharedMemorySize, lds_bytes);

  pack_w<<<dim3(896), dim3(256), 0, stream>>>(Wih0, Whh0, Wih1, Whh1, PA, PB);
  lstm_block<<<dim3(64), dim3(512), lds_bytes, stream>>>(
      x, PA, PB, b0, b1, Wout, bout, out);
}

// Round 18
// 1227.447 us; speedup vs baseline: 1.4714x; 1.0585x over previous
//
#include <hip/hip_runtime.h>
#include <math.h>

namespace {

constexpr int T_STEPS = 512;

typedef _Float16 h8v __attribute__((ext_vector_type(8)));
typedef _Float16 h2v __attribute__((ext_vector_type(2)));
typedef float    f4v __attribute__((ext_vector_type(4)));

// rcp-based activations (R13-proven).
__device__ __forceinline__ float sigf(float v) {
  return __builtin_amdgcn_rcpf(1.0f + __builtin_amdgcn_exp2f(-1.442695041f * v));
}
__device__ __forceinline__ float tanh_(float v) {
  return 2.0f * __builtin_amdgcn_rcpf(1.0f + __builtin_amdgcn_exp2f(-2.885390082f * v)) - 1.0f;
}

// Pack weights into MFMA B-fragment load order, fp16 (verified on HW R3-R17).
// PA (layer0): frag f = (w*4+q)*6 + ks: gate = 16*(8q+w)+(l&15),
//   k = 32*ks + 8*(l>>4) + j ; ks 0-1 Wih0, ks 2-5 Whh0.
// PB (layer1): 8 ks: 0-3 Wih1, 4-7 Whh1.
__global__ void pack_w(const float* __restrict__ Wih0, const float* __restrict__ Whh0,
                       const float* __restrict__ Wih1, const float* __restrict__ Whh1,
                       _Float16* __restrict__ PA, _Float16* __restrict__ PB) {
  int idx = blockIdx.x * 256 + threadIdx.x;
  if (idx < 98304) {
    int j = idx & 7, l = (idx >> 3) & 63;
    int f = idx >> 9;
    int ks = f % 6, wq = f / 6;
    int q = wq & 3, w = wq >> 2;
    int gate = 16 * (8 * q + w) + (l & 15);
    int k = 32 * ks + ((l >> 4) << 3) + j;
    float v = (k < 64) ? Wih0[gate * 64 + k] : Whh0[gate * 128 + (k - 64)];
    PA[idx] = (_Float16)v;
  } else if (idx < 98304 + 131072) {
    int i = idx - 98304;
    int j = i & 7, l = (i >> 3) & 63;
    int f = i >> 9;
    int ks = f & 7, wq = f >> 3;
    int q = wq & 3, w = wq >> 2;
    int gate = 16 * (8 * q + w) + (l & 15);
    int k = 32 * ks + ((l >> 4) << 3) + j;
    float v = (k < 128) ? Wih1[gate * 128 + k] : Whh1[gate * 128 + (k - 128)];
    PB[i] = (_Float16)v;
  }
}

// R13 structure (best: 1291us) at DOUBLE CU COUNT: 128 blocks x 8 batch rows
// (was 64 x 16). The dense Whh recurrence pins all 128 units to one block,
// but batch rows split freely -- per-CU cell count halves (trans/VALU, the
// measured #1 pipe at 42% busy, halves) while MFMA/LDS/L2 per block stay
// constant (M=16 tiles regardless of valid rows). Rows 8-15 of the activation
// tiles are zero-initialized once; they compute finite garbage that is
// row-local and never written out. LDS (151 KB) still forces 1 block/CU ->
// 128 of 256 CUs active. Everything else identical to R13: 512 threads
// (8 waves, 2/SIMD), fused iter j = L0 step j + L1 step j-1, ONE barrier/iter,
// wave w owns units [16w,16w+16) x 4 gates both layers, lane-local cell
// update, c fp32 in registers, Whh1 LDS-resident, W0/Wih1 L2-remat.
__global__ __attribute__((amdgpu_waves_per_eu(2, 2))) __launch_bounds__(512)
void lstm_block(
    const float* __restrict__ x,
    const _Float16* __restrict__ PA, const _Float16* __restrict__ PB,
    const float* __restrict__ b0, const float* __restrict__ b1,
    const float* __restrict__ Wout, const float* __restrict__ bout,
    float* __restrict__ out) {
  extern __shared__ char smem[];
  h8v* whh = (h8v*)smem;  // Whh1 B-frags: [32 wq][4 ks4][64 l] = 128 KB
  _Float16(*h0t)[4][64][8] = (_Float16(*)[4][64][8])(smem + 131072);          // [2][4][64][8] 8 KB
  _Float16(*h1t)[4][64][8] = (_Float16(*)[4][64][8])(smem + 131072 + 8192);   // 8 KB
  _Float16(*xt)[2][64][8]  = (_Float16(*)[2][64][8])(smem + 131072 + 16384);  // [2][2][64][8] 4 KB

  const int tid = threadIdx.x;
  const int g = blockIdx.x;
  const int w = tid >> 6, l = tid & 63;
  const int lo = l & 15, hi = l >> 4;
  const int unit = 16 * w + lo;
  const int kb_w = w >> 1;
  const int sub_w = (2 * w + (lo >> 3)) & 3;
  const int lanep = sub_w * 16 + hi * 4;  // + r
  const int jw = lo & 7;

  // ---- persistent register weights (compiler may remat -- measured OK) ----
  const h8v* PAv = (const h8v*)PA;
  const h8v* PBv = (const h8v*)PB;
  h8v W0[4][6], W1[4][4];
#pragma unroll
  for (int q = 0; q < 4; ++q) {
#pragma unroll
    for (int ks = 0; ks < 6; ++ks) W0[q][ks] = PAv[((w * 4 + q) * 6 + ks) * 64 + l];
#pragma unroll
    for (int ks = 0; ks < 4; ++ks) W1[q][ks] = PBv[((w * 4 + q) * 8 + ks) * 64 + l];
  }
#pragma unroll
  for (int q = 0; q < 4; ++q) {
#pragma unroll
    for (int ks = 0; ks < 6; ++ks) asm volatile("" : "+v"(W0[q][ks]));
#pragma unroll
    for (int ks = 0; ks < 4; ++ks) asm volatile("" : "+v"(W1[q][ks]));
  }
  float bA[4], bB[4];
#pragma unroll
  for (int q = 0; q < 4; ++q) { bA[q] = b0[unit + 128 * q]; bB[q] = b1[unit + 128 * q]; }
  float c0[4] = {0.f, 0.f, 0.f, 0.f}, c1[4] = {0.f, 0.f, 0.f, 0.f};

  // ---- stage Whh1 fragments into LDS ----
  for (int i = tid; i < 8192; i += 512) {
    int l2 = i & 63, f = i >> 6;
    int ks4 = f & 3, wq = f >> 2;
    whh[i] = PBv[(wq * 8 + 4 + ks4) * 64 + l2];
  }
  // ---- zero h0t/h1t and BOTH xt buffers (rows 8-15 stay zero forever) ----
  {
    unsigned int* z0 = (unsigned int*)h0t;
    unsigned int* z1 = (unsigned int*)h1t;
    unsigned int* z2 = (unsigned int*)xt;
    for (int i = tid; i < 2048; i += 512) { z0[i] = 0u; z1[i] = 0u; }
    for (int i = tid; i < 1024; i += 512) { z2[i] = 0u; }
  }
  __syncthreads();
  // ---- stage x(0) rows 0-7 ----
  if (tid < 256) {
    int row = tid >> 5, kk = (tid & 31) << 1;
    const float* xp = x + (((long)(g * 8 + row)) * T_STEPS + 0) * 64 + kk;
    float2 v = *(const float2*)xp;
    h2v pxv; pxv.x = (_Float16)v.x; pxv.y = (_Float16)v.y;
    *(h2v*)&xt[0][kk >> 5][(((kk >> 3) & 3) * 16) + row][kk & 7] = pxv;
  }
  __syncthreads();

  // Fused: iter j = A(j) [layer0 step j] + B(j-1) [layer1 step j-1].
  for (int j = 0; j <= T_STEPS; ++j) {
    const int p = j & 1;

    // shared h0(j-1) fragments (A-operand for BOTH layers)
    h8v h00 = *(const h8v*)&h0t[p][0][l][0];
    h8v h01 = *(const h8v*)&h0t[p][1][l][0];
    h8v h02 = *(const h8v*)&h0t[p][2][l][0];
    h8v h03 = *(const h8v*)&h0t[p][3][l][0];

    if (j < T_STEPS) {
      // ---- A(j): layer 0 computes h0(j) ----
      h8v ax0 = *(const h8v*)&xt[p][0][l][0];
      h8v ax1 = *(const h8v*)&xt[p][1][l][0];
      f4v accA[4];
#pragma unroll
      for (int q = 0; q < 4; ++q) {
        f4v z = {bA[q], bA[q], bA[q], bA[q]};
        z = __builtin_amdgcn_mfma_f32_16x16x32_f16(ax0, W0[q][0], z, 0, 0, 0);
        z = __builtin_amdgcn_mfma_f32_16x16x32_f16(ax1, W0[q][1], z, 0, 0, 0);
        z = __builtin_amdgcn_mfma_f32_16x16x32_f16(h00, W0[q][2], z, 0, 0, 0);
        z = __builtin_amdgcn_mfma_f32_16x16x32_f16(h01, W0[q][3], z, 0, 0, 0);
        z = __builtin_amdgcn_mfma_f32_16x16x32_f16(h02, W0[q][4], z, 0, 0, 0);
        z = __builtin_amdgcn_mfma_f32_16x16x32_f16(h03, W0[q][5], z, 0, 0, 0);
        accA[q] = z;
      }
#pragma unroll
      for (int r = 0; r < 4; ++r) {
        float cn = sigf(accA[1][r]) * c0[r] + sigf(accA[0][r]) * tanh_(accA[2][r]);
        c0[r] = cn;
        float hv = sigf(accA[3][r]) * tanh_(cn);
        h0t[p ^ 1][kb_w][lanep + r][jw] = (_Float16)hv;
      }
      if (j + 1 < T_STEPS && tid < 256) {  // stage x(j+1) rows 0-7
        int row = tid >> 5, kk = (tid & 31) << 1;
        const float* xp = x + (((long)(g * 8 + row)) * T_STEPS + (j + 1)) * 64 + kk;
        float2 v = *(const float2*)xp;
        h2v pxv; pxv.x = (_Float16)v.x; pxv.y = (_Float16)v.y;
        *(h2v*)&xt[p ^ 1][kk >> 5][(((kk >> 3) & 3) * 16) + row][kk & 7] = pxv;
      }
    }

    if (j >= 1) {
      // ---- B(j-1): layer 1 computes h1(j-1) ----
      h8v f10 = *(const h8v*)&h1t[p][0][l][0];
      h8v f11 = *(const h8v*)&h1t[p][1][l][0];
      h8v f12 = *(const h8v*)&h1t[p][2][l][0];
      h8v f13 = *(const h8v*)&h1t[p][3][l][0];
      f4v accB[4];
#pragma unroll
      for (int q = 0; q < 4; ++q) {
        const h8v* wb = &whh[((w * 4 + q) * 4) * 64 + l];
        h8v wh0 = wb[0];
        h8v wh1 = wb[64];
        h8v wh2 = wb[128];
        h8v wh3 = wb[192];
        f4v z = {bB[q], bB[q], bB[q], bB[q]};
        z = __builtin_amdgcn_mfma_f32_16x16x32_f16(h00, W1[q][0], z, 0, 0, 0);
        z = __builtin_amdgcn_mfma_f32_16x16x32_f16(h01, W1[q][1], z, 0, 0, 0);
        z = __builtin_amdgcn_mfma_f32_16x16x32_f16(h02, W1[q][2], z, 0, 0, 0);
        z = __builtin_amdgcn_mfma_f32_16x16x32_f16(h03, W1[q][3], z, 0, 0, 0);
        z = __builtin_amdgcn_mfma_f32_16x16x32_f16(f10, wh0, z, 0, 0, 0);
        z = __builtin_amdgcn_mfma_f32_16x16x32_f16(f11, wh1, z, 0, 0, 0);
        z = __builtin_amdgcn_mfma_f32_16x16x32_f16(f12, wh2, z, 0, 0, 0);
        z = __builtin_amdgcn_mfma_f32_16x16x32_f16(f13, wh3, z, 0, 0, 0);
        accB[q] = z;
      }
#pragma unroll
      for (int r = 0; r < 4; ++r) {
        float cn = sigf(accB[1][r]) * c1[r] + sigf(accB[0][r]) * tanh_(accB[2][r]);
        c1[r] = cn;
        float hv = sigf(accB[3][r]) * tanh_(cn);
        h1t[p ^ 1][kb_w][lanep + r][jw] = (_Float16)hv;
      }
    }
    __syncthreads();
  }

  // ---- output projection: y = h1(T-1) . Wout^T + bout ; h1(T-1) in h1t[1] ----
  if (tid < 8) {
    float acc = bout[0];
#pragma unroll 4
    for (int u = 0; u < 128; ++u) {
      float hval = (float)h1t[1][u >> 5][(((u >> 3) & 3) * 16) + tid][u & 7];
      acc = fmaf(hval, Wout[u], acc);
    }
    out[g * 8 + tid] = acc;
  }
}

}  // namespace

extern "C" void kernel_launch(void* const* d_in, const int* in_sizes, int n_in,
                              void* d_out, int out_size, void* d_ws, size_t ws_size,
                              hipStream_t stream) {
  const float* x    = (const float*)d_in[0];
  const float* Wih0 = (const float*)d_in[1];
  const float* Whh0 = (const float*)d_in[2];
  const float* b0   = (const float*)d_in[3];
  const float* Wih1 = (const float*)d_in[4];
  const float* Whh1 = (const float*)d_in[5];
  const float* b1   = (const float*)d_in[6];
  const float* Wout = (const float*)d_in[7];
  const float* bout = (const float*)d_in[8];
  float* out = (float*)d_out;

  char* ws = (char*)d_ws;
  _Float16* PA = (_Float16*)ws;             // 196608 B
  _Float16* PB = (_Float16*)(ws + 196608);  // 262144 B

  const int lds_bytes = 131072 + 8192 + 8192 + 4096;  // 151552
  hipFuncSetAttribute((const void*)lstm_block,
                      hipFuncAttributeMaxDynamicSharedMemorySize, lds_bytes);

  pack_w<<<dim3(896), dim3(256), 0, stream>>>(Wih0, Whh0, Wih1, Whh1, PA, PB);
  lstm_block<<<dim3(128), dim3(512), lds_bytes, stream>>>(
      x, PA, PB, b0, b1, Wout, bout, out);
}